// Round 8
// baseline (525.258 us; speedup 1.0000x reference)
//
#include <hip/hip_runtime.h>
#include <hip/hip_cooperative_groups.h>
#include <math.h>

namespace cg = cooperative_groups;

#define Bsz 4
#define Nseq 2048
#define Cdim 512
#define Hn 8
#define Dh 64
#define TK 256
#define BH (Bsz*Hn)          // 32
#define MROWS (Bsz*Nseq)     // 8192
#define QKVC 1536

typedef __attribute__((ext_vector_type(8))) short bf16x8;
typedef __attribute__((ext_vector_type(4))) float f32x4;

__device__ __forceinline__ unsigned short f2bf(float x) {
    unsigned u = __float_as_uint(x);
    unsigned r = (u + 0x7fffu + ((u >> 16) & 1u)) >> 16;   // RNE
    return (unsigned short)r;
}
__device__ __forceinline__ float bf2f(unsigned short h) {
    return __uint_as_float((unsigned)h << 16);
}
__device__ __forceinline__ void split8(const float* p, bf16x8& h8, bf16x8& l8) {
    float4 u0 = *(const float4*)p;
    float4 u1 = *(const float4*)(p + 4);
    float vv[8] = {u0.x, u0.y, u0.z, u0.w, u1.x, u1.y, u1.z, u1.w};
    #pragma unroll
    for (int j = 0; j < 8; ++j) {
        unsigned short hv = f2bf(vv[j]);
        h8[j] = (short)hv;
        l8[j] = (short)f2bf(vv[j] - bf2f(hv));
    }
}

// One cooperative kernel, 256 blocks x 256 threads, 1 block/CU
// (139,264 B static LDS guarantees co-residency on 256 CUs).
__global__ __launch_bounds__(256, 1) void mega(const float* __restrict__ x,
                                               const float* __restrict__ w_qkv,
                                               const float* __restrict__ w_out,
                                               const float* __restrict__ b_out,
                                               float* __restrict__ out,
                                               float* __restrict__ ws) {
    cg::grid_group gridg = cg::this_grid();
    __shared__ __align__(16) float S[34816];     // 139,264 B

    // ---- workspace layout
    bf16x8* Bp_hi = (bf16x8*)ws;                                  // 393,216 f
    bf16x8* Bp_lo = (bf16x8*)(ws + 393216);                       // 393,216 f
    float* xpart  = ws + 786432;                                  // 32,768 f
    float* proj   = xpart + 32768;                                // 32,768 f
    float* sv_g   = proj + 32768;                                 // 2,048 f
    float* svsel  = sv_g + 2048;                                  // 4,096 f
    float* ubase  = svsel + 4096;                                 // 2,048 f
    float* rsc    = ubase + 2048;                                 // 65,536 f
    float* csc    = rsc + (size_t)BH * Nseq;                      // 65,536 f
    int*   ridx   = (int*)(csc + (size_t)BH * Nseq);              // 8,192 i
    int*   cidx   = ridx + BH * TK;                               // 8,192 i
    int*   rankmap = cidx + BH * TK;                              // 65,536 i
    float* Qs_g   = (float*)(rankmap + (size_t)BH * Nseq);        // 524,288 f
    float* Kt_g   = Qs_g + (size_t)BH * TK * 64;                  // 524,288 f
    float* Vs_g   = Kt_g + (size_t)BH * TK * 64;                  // 524,288 f
    float* deltaout = Vs_g + (size_t)BH * TK * 64;                // 4,194,304 f

    int blk = blockIdx.x, tid = threadIdx.x;

    // ================= P1: x column-sum partials + w_qkv B-pack =================
    for (int item = blk; item < 448; item += 256) {
        if (item < 64) {
            int b = item >> 4, chunk = item & 15;
            float s0 = 0.f, s1 = 0.f;
            const float* xb = x + ((size_t)b * Nseq + chunk * 128) * Cdim;
            #pragma unroll 4
            for (int r = 0; r < 128; ++r) {
                s0 += xb[(size_t)r * Cdim + tid];
                s1 += xb[(size_t)r * Cdim + tid + 256];
            }
            xpart[(size_t)(b * 16 + chunk) * Cdim + tid] = s0;
            xpart[(size_t)(b * 16 + chunk) * Cdim + tid + 256] = s1;
        } else {
            int pid = item - 64;
            int nt = pid % 96, ktg = pid / 96;
            int kt = ktg * 4 + (tid >> 6);
            int lane = tid & 63;
            int c = nt * 16 + (lane & 15);
            int kbase = kt * 32 + (lane >> 4) * 8;
            bf16x8 h, l;
            #pragma unroll
            for (int j = 0; j < 8; ++j) {
                float v = w_qkv[(size_t)(kbase + j) * QKVC + c];
                unsigned short hv = f2bf(v);
                h[j] = (short)hv;
                l[j] = (short)f2bf(v - bf2f(hv));
            }
            int idx = (nt * 16 + kt) * 64 + lane;
            Bp_hi[idx] = h;
            Bp_lo[idx] = l;
        }
    }
    gridg.sync();

    // ================= P2: projections / sv / ubase =================
    {
        float* xs   = S;            // 512
        float* red  = S + 512;      // 256
        float* mean = S + 768;      // 64
        float* p2   = S + 832;      // 256
        float* svs  = S + 1088;     // 512
        for (int item = blk; item < 272; item += 256) {
            int b = item / 68, j = item % 68;
            {
                float s0 = 0.f, s1 = 0.f;
                for (int c16 = 0; c16 < 16; ++c16) {
                    const float* xp = xpart + (size_t)(b * 16 + c16) * Cdim;
                    s0 += xp[tid];
                    s1 += xp[tid + 256];
                }
                xs[tid] = s0; xs[tid + 256] = s1;
            }
            __syncthreads();
            if (j < 64) {
                int slot = j >> 2, q = j & 3;
                int type = slot >> 3, h = slot & 7;
                int moff = (type ? 0 : 512) + h * 64;
                int woff = (type ? 512 : 0) + h * 64;
                {
                    int d = tid & 63, kq = tid >> 6;
                    float s = 0.f;
                    for (int k = kq * 128; k < kq * 128 + 128; ++k)
                        s += xs[k] * w_qkv[(size_t)k * QKVC + moff + d];
                    red[kq * 64 + d] = s;
                }
                __syncthreads();
                if (tid < 64)
                    mean[tid] = (red[tid] + red[64 + tid] + red[128 + tid] + red[192 + tid]) * (1.0f / Nseq);
                __syncthreads();
                int c = q * 128 + (tid & 127), half = tid >> 7;
                float s = 0.f;
                const float4* wp = (const float4*)(w_qkv + (size_t)c * QKVC + woff + half * 32);
                const float4* mp = (const float4*)(mean + half * 32);
                #pragma unroll
                for (int d4 = 0; d4 < 8; ++d4) {
                    float4 w4 = wp[d4], m4 = mp[d4];
                    s += w4.x * m4.x + w4.y * m4.y + w4.z * m4.z + w4.w * m4.w;
                }
                p2[half * 128 + (tid & 127)] = s;
                __syncthreads();
                if (tid < 128)
                    proj[(size_t)(b * 16 + slot) * 512 + q * 128 + tid] = p2[tid] + p2[128 + tid];
                __syncthreads();
            } else {
                int q = j - 64;
                {
                    float s0 = 0.f, s1 = 0.f;
                    for (int k = 0; k < 512; ++k) {
                        float xv = xs[k];
                        const float* wr = w_qkv + (size_t)k * QKVC + 1024;
                        s0 += xv * wr[tid];
                        s1 += xv * wr[tid + 256];
                    }
                    svs[tid] = s0; svs[tid + 256] = s1;
                    if (q == 0) { sv_g[b * 512 + tid] = s0; sv_g[b * 512 + tid + 256] = s1; }
                }
                __syncthreads();
                int c = q * 128 + (tid & 127), half = tid >> 7;
                float s = 0.f;
                for (int k = half * 256; k < half * 256 + 256; ++k)
                    s += svs[k] * (1.0f / Nseq) * w_out[(size_t)k * 512 + c];
                p2[half * 128 + (tid & 127)] = s;
                __syncthreads();
                if (tid < 128)
                    ubase[b * 512 + q * 128 + tid] = p2[tid] + p2[128 + tid] + b_out[q * 128 + tid];
                __syncthreads();
            }
        }
    }
    gridg.sync();

    // ================= P3: scores = 0.125 * x @ proj =================
    if (blk < 128) {
        int b = blk >> 5, ch = blk & 31;
        float4* pj4 = (float4*)S;          // 2048 float4
        float* part = S + 8192;            // [4][64][17]
        for (int i = tid; i < 2048; i += 256)
            pj4[i] = ((const float4*)(proj + (size_t)b * 16 * 512))[i];
        __syncthreads();
        int w = tid >> 6, lane = tid & 63;
        int row = ch * 64 + lane;
        const float4* xr = (const float4*)(x + ((size_t)b * Nseq + row) * Cdim + w * 128);
        float acc[16];
        #pragma unroll
        for (int s = 0; s < 16; ++s) acc[s] = 0.f;
        for (int c4 = 0; c4 < 32; ++c4) {
            float4 xv = xr[c4];
            #pragma unroll
            for (int s = 0; s < 16; ++s) {
                float4 p = pj4[s * 128 + w * 32 + c4];
                acc[s] += xv.x * p.x + xv.y * p.y + xv.z * p.z + xv.w * p.w;
            }
        }
        #pragma unroll
        for (int s = 0; s < 16; ++s) part[(w * 64 + lane) * 17 + s] = acc[s];
        __syncthreads();
        for (int job = tid; job < 1024; job += 256) {
            int rl = job >> 4, s = job & 15;
            float v = (part[rl * 17 + s] + part[(64 + rl) * 17 + s] +
                       part[(128 + rl) * 17 + s] + part[(192 + rl) * 17 + s]) * 0.125f;
            int i = ch * 64 + rl;
            int h = s & 7;
            if (s < 8) rsc[(size_t)(b * 8 + h) * Nseq + i] = v;
            else       csc[(size_t)(b * 8 + h) * Nseq + i] = v;
        }
    }
    gridg.sync();

    // ================= P4: top-256 by rank counting =================
    if (blk < 128) {
        int bh = blk >> 2, which = (blk >> 1) & 1, half = blk & 1;
        const float* sin = which ? (csc + (size_t)bh * Nseq) : (rsc + (size_t)bh * Nseq);
        int* outp = which ? (cidx + bh * TK) : (ridx + bh * TK);
        unsigned long long* keys = (unsigned long long*)S;    // 2048 ull
        for (int i = tid; i < Nseq; i += 256) {
            unsigned u = __float_as_uint(sin[i]);
            u = (u & 0x80000000u) ? ~u : (u | 0x80000000u);
            keys[i] = ((unsigned long long)u << 32) | (unsigned)(Nseq - 1 - i);
        }
        __syncthreads();
        int i0 = half * 1024 + tid * 4;
        unsigned long long k0 = keys[i0], k1 = keys[i0 + 1], k2 = keys[i0 + 2], k3 = keys[i0 + 3];
        int r0 = 0, r1 = 0, r2 = 0, r3 = 0;
        #pragma unroll 8
        for (int j = 0; j < Nseq; ++j) {
            unsigned long long kj = keys[j];
            r0 += kj > k0; r1 += kj > k1; r2 += kj > k2; r3 += kj > k3;
        }
        if (r0 < TK) outp[r0] = i0;
        if (r1 < TK) outp[r1] = i0 + 1;
        if (r2 < TK) outp[r2] = i0 + 2;
        if (r3 < TK) outp[r3] = i0 + 3;
        if (which == 0) {
            rankmap[(size_t)bh * Nseq + i0]     = (r0 < TK) ? r0 : -1;
            rankmap[(size_t)bh * Nseq + i0 + 1] = (r1 < TK) ? r1 : -1;
            rankmap[(size_t)bh * Nseq + i0 + 2] = (r2 < TK) ? r2 : -1;
            rankmap[(size_t)bh * Nseq + i0 + 3] = (r3 < TK) ? r3 : -1;
        }
    }
    gridg.sync();

    // ================= P5: gather GEMM (selected Q / K^T / V) =================
    if (blk < 128) {
        int which = blk & 1, rh = (blk >> 1) & 1, bh = blk >> 2;
        int b = bh >> 3, h = bh & 7;
        int wv = tid >> 6, lane = tid & 63;
        float* red = S;   // [4][64]
        const int* idx = (which == 0 ? ridx : cidx) + bh * TK;
        const float* ap[2];
        #pragma unroll
        for (int mi = 0; mi < 2; ++mi) {
            int sel = idx[rh * 128 + wv * 32 + mi * 16 + (lane & 15)];
            ap[mi] = x + ((size_t)(b * Nseq + sel)) * Cdim + ((lane >> 4) * 8);
        }
        int cl = lane & 15, rq = (lane >> 4) * 4;
        if (which == 0) {
            f32x4 acc[2][4];
            #pragma unroll
            for (int a = 0; a < 2; ++a)
                #pragma unroll
                for (int c = 0; c < 4; ++c) acc[a][c] = (f32x4){0.f, 0.f, 0.f, 0.f};
            #pragma unroll 2
            for (int kt = 0; kt < 16; ++kt) {
                bf16x8 ah[2], al[2], bh8[4], bl8[4];
                #pragma unroll
                for (int mi = 0; mi < 2; ++mi) split8(ap[mi] + kt * 32, ah[mi], al[mi]);
                #pragma unroll
                for (int ni = 0; ni < 4; ++ni) {
                    int bi = ((h * 4 + ni) * 16 + kt) * 64 + lane;
                    bh8[ni] = Bp_hi[bi]; bl8[ni] = Bp_lo[bi];
                }
                #pragma unroll
                for (int mi = 0; mi < 2; ++mi)
                    #pragma unroll
                    for (int ni = 0; ni < 4; ++ni) {
                        acc[mi][ni] = __builtin_amdgcn_mfma_f32_16x16x32_bf16(ah[mi], bh8[ni], acc[mi][ni], 0, 0, 0);
                        acc[mi][ni] = __builtin_amdgcn_mfma_f32_16x16x32_bf16(ah[mi], bl8[ni], acc[mi][ni], 0, 0, 0);
                        acc[mi][ni] = __builtin_amdgcn_mfma_f32_16x16x32_bf16(al[mi], bh8[ni], acc[mi][ni], 0, 0, 0);
                    }
            }
            #pragma unroll
            for (int ni = 0; ni < 4; ++ni)
                #pragma unroll
                for (int mi = 0; mi < 2; ++mi)
                    #pragma unroll
                    for (int r = 0; r < 4; ++r) {
                        int row = rh * 128 + wv * 32 + mi * 16 + rq + r;
                        Qs_g[((size_t)bh * TK + row) * 64 + ni * 16 + cl] = acc[mi][ni][r];
                    }
        } else {
            f32x4 acc[2][8];
            #pragma unroll
            for (int a = 0; a < 2; ++a)
                #pragma unroll
                for (int c = 0; c < 8; ++c) acc[a][c] = (f32x4){0.f, 0.f, 0.f, 0.f};
            #pragma unroll 2
            for (int kt = 0; kt < 16; ++kt) {
                bf16x8 ah[2], al[2], bh8[8], bl8[8];
                #pragma unroll
                for (int mi = 0; mi < 2; ++mi) split8(ap[mi] + kt * 32, ah[mi], al[mi]);
                #pragma unroll
                for (int ni = 0; ni < 8; ++ni) {
                    int nt16 = (ni < 4) ? (32 + h * 4 + ni) : (64 + h * 4 + (ni - 4));
                    int bi = (nt16 * 16 + kt) * 64 + lane;
                    bh8[ni] = Bp_hi[bi]; bl8[ni] = Bp_lo[bi];
                }
                #pragma unroll
                for (int mi = 0; mi < 2; ++mi)
                    #pragma unroll
                    for (int ni = 0; ni < 8; ++ni) {
                        acc[mi][ni] = __builtin_amdgcn_mfma_f32_16x16x32_bf16(ah[mi], bh8[ni], acc[mi][ni], 0, 0, 0);
                        acc[mi][ni] = __builtin_amdgcn_mfma_f32_16x16x32_bf16(ah[mi], bl8[ni], acc[mi][ni], 0, 0, 0);
                        acc[mi][ni] = __builtin_amdgcn_mfma_f32_16x16x32_bf16(al[mi], bh8[ni], acc[mi][ni], 0, 0, 0);
                    }
            }
            #pragma unroll
            for (int ni = 0; ni < 4; ++ni) {
                int d = ni * 16 + cl;
                #pragma unroll
                for (int mi = 0; mi < 2; ++mi)
                    #pragma unroll
                    for (int r = 0; r < 4; ++r) {
                        int row = rh * 128 + wv * 32 + mi * 16 + rq + r;
                        Kt_g[((size_t)bh * 64 + d) * TK + row] = acc[mi][ni][r];
                    }
            }
            #pragma unroll
            for (int ni = 0; ni < 4; ++ni) {
                int d = ni * 16 + cl;
                float s = 0.f;
                #pragma unroll
                for (int mi = 0; mi < 2; ++mi)
                    #pragma unroll
                    for (int r = 0; r < 4; ++r) {
                        int row = rh * 128 + wv * 32 + mi * 16 + rq + r;
                        Vs_g[((size_t)bh * TK + row) * 64 + d] = acc[mi][4 + ni][r];
                        s += acc[mi][4 + ni][r];
                    }
                s += __shfl_xor(s, 16, 64);
                s += __shfl_xor(s, 32, 64);
                if (lane < 16) red[wv * 64 + ni * 16 + lane] = s;
            }
            __syncthreads();
            if (tid < 64)
                svsel[(bh * 2 + rh) * 64 + tid] = red[tid] + red[64 + tid] + red[128 + tid] + red[192 + tid];
        }
    }
    gridg.sync();

    // ================= P6: fused attention + delta @ w_out =================
    {
        int bh = blk >> 3, rblk = blk & 7;
        int b = bh >> 3, h = bh & 7;
        int wave = tid >> 6, lane = tid & 63;
        float* Kt = S;                 // 16384 f (reused as E)
        float* Vs = S + 16384;         // 16384 f
        float* dQ = S + 32768;         // 2048 f: Qs4 then delta
        float4* Kt4 = (float4*)Kt;
        float4* Vs4 = (float4*)Vs;
        float4* Qs4 = (float4*)dQ;
        {
            const float4* ks = (const float4*)(Kt_g + (size_t)bh * 64 * TK);
            const float4* vs = (const float4*)(Vs_g + (size_t)bh * TK * 64);
            for (int i = tid; i < 4096; i += 256) { Kt4[i] = ks[i]; Vs4[i] = vs[i]; }
            const float4* qs = (const float4*)(Qs_g + ((size_t)bh * TK + rblk * 32) * 64);
            for (int i = tid; i < 512; i += 256) Qs4[i] = qs[i];
        }
        __syncthreads();

        int iw0 = wave * 8;
        float e[8][4];
        #pragma unroll
        for (int r = 0; r < 8; ++r)
            #pragma unroll
            for (int c = 0; c < 4; ++c) e[r][c] = 0.f;
        for (int d4 = 0; d4 < 16; ++d4) {
            float4 k0 = Kt4[(4 * d4 + 0) * 64 + lane];
            float4 k1 = Kt4[(4 * d4 + 1) * 64 + lane];
            float4 k2 = Kt4[(4 * d4 + 2) * 64 + lane];
            float4 k3 = Kt4[(4 * d4 + 3) * 64 + lane];
            #pragma unroll
            for (int r = 0; r < 8; ++r) {
                float4 q4 = Qs4[(iw0 + r) * 16 + d4];
                e[r][0] += q4.x * k0.x + q4.y * k1.x + q4.z * k2.x + q4.w * k3.x;
                e[r][1] += q4.x * k0.y + q4.y * k1.y + q4.z * k2.y + q4.w * k3.y;
                e[r][2] += q4.x * k0.z + q4.y * k1.z + q4.z * k2.z + q4.w * k3.z;
                e[r][3] += q4.x * k0.w + q4.y * k1.w + q4.z * k2.w + q4.w * k3.w;
            }
        }
        float um[8], iz[8];
        #pragma unroll
        for (int r = 0; r < 8; ++r) {
            float s0 = e[r][0] * 0.125f, s1 = e[r][1] * 0.125f;
            float s2 = e[r][2] * 0.125f, s3 = e[r][3] * 0.125f;
            float mx = fmaxf(fmaxf(s0, s1), fmaxf(s2, s3));
            #pragma unroll
            for (int off = 32; off; off >>= 1) mx = fmaxf(mx, __shfl_xor(mx, off, 64));
            mx = fmaxf(mx, 0.0f);
            float e0 = __expf(s0 - mx), e1 = __expf(s1 - mx);
            float e2 = __expf(s2 - mx), e3 = __expf(s3 - mx);
            float zs = e0 + e1 + e2 + e3;
            #pragma unroll
            for (int off = 32; off; off >>= 1) zs += __shfl_xor(zs, off, 64);
            um[r] = __expf(-mx);
            iz[r] = 1.0f / ((float)(Nseq - TK) * um[r] + zs);
            e[r][0] = e0; e[r][1] = e1; e[r][2] = e2; e[r][3] = e3;
        }
        __syncthreads();
        float4* E4 = (float4*)Kt;
        #pragma unroll
        for (int r = 0; r < 8; ++r)
            E4[(iw0 + r) * 64 + lane] = (float4){e[r][0], e[r][1], e[r][2], e[r][3]};
        __syncthreads();

        float svd = sv_g[b * 512 + h * 64 + lane];
        float sadj = svd - (svsel[(bh * 2 + 0) * 64 + lane] + svsel[(bh * 2 + 1) * 64 + lane]);
        float uval = svd * (1.0f / Nseq);
        float acc[8];
        #pragma unroll
        for (int r = 0; r < 8; ++r) acc[r] = 0.f;
        for (int j4 = 0; j4 < 64; ++j4) {
            float v0 = Vs[(4 * j4 + 0) * 64 + lane];
            float v1 = Vs[(4 * j4 + 1) * 64 + lane];
            float v2 = Vs[(4 * j4 + 2) * 64 + lane];
            float v3 = Vs[(4 * j4 + 3) * 64 + lane];
            #pragma unroll
            for (int r = 0; r < 8; ++r) {
                float4 e4 = E4[(iw0 + r) * 64 + j4];
                acc[r] += e4.x * v0 + e4.y * v1 + e4.z * v2 + e4.w * v3;
            }
        }
        __syncthreads();      // done with Qs4 view; reuse dQ for delta
        #pragma unroll
        for (int r = 0; r < 8; ++r) {
            float outv = (um[r] * sadj + acc[r]) * iz[r];
            dQ[(iw0 + r) * 64 + lane] = outv - uval;
        }
        __syncthreads();

        // delta(32x64) @ w_out_h(64x512) -> deltaout rows
        float dacc[8][8];
        #pragma unroll
        for (int r = 0; r < 8; ++r)
            #pragma unroll
            for (int c = 0; c < 8; ++c) dacc[r][c] = 0.f;
        const float* wbase = w_out + (size_t)(h * 64) * 512 + lane * 8;
        for (int k = 0; k < 64; ++k) {
            float4 wa = *(const float4*)(wbase + (size_t)k * 512);
            float4 wb = *(const float4*)(wbase + (size_t)k * 512 + 4);
            #pragma unroll
            for (int r = 0; r < 8; ++r) {
                float dv = dQ[(iw0 + r) * 64 + k];
                dacc[r][0] += dv * wa.x; dacc[r][1] += dv * wa.y;
                dacc[r][2] += dv * wa.z; dacc[r][3] += dv * wa.w;
                dacc[r][4] += dv * wb.x; dacc[r][5] += dv * wb.y;
                dacc[r][6] += dv * wb.z; dacc[r][7] += dv * wb.w;
            }
        }
        #pragma unroll
        for (int r = 0; r < 8; ++r) {
            int row = rblk * 32 + iw0 + r;
            float* dp = deltaout + ((size_t)bh * TK + row) * 512 + lane * 8;
            *(float4*)dp = (float4){dacc[r][0], dacc[r][1], dacc[r][2], dacc[r][3]};
            *(float4*)(dp + 4) = (float4){dacc[r][4], dacc[r][5], dacc[r][6], dacc[r][7]};
        }
    }
    gridg.sync();

    // ================= P7: compose output =================
    for (int item = blk; item < 2048; item += 256) {
        int r0 = item * 4;
        int b = r0 >> 11;
        float u0 = ubase[b * 512 + tid];
        float u1 = ubase[b * 512 + 256 + tid];
        for (int rr = 0; rr < 4; ++rr) {
            int i = (r0 + rr) & 2047;
            float a0 = u0, a1 = u1;
            #pragma unroll
            for (int h = 0; h < 8; ++h) {
                int rk = rankmap[(size_t)(b * 8 + h) * Nseq + i];
                if (rk >= 0) {
                    const float* dp = deltaout + ((size_t)(b * 8 + h) * TK + rk) * 512;
                    a0 += dp[tid];
                    a1 += dp[256 + tid];
                }
            }
            float* op = out + ((size_t)b * Nseq + i) * 512;
            op[tid] = a0;
            op[256 + tid] = a1;
        }
    }
}

extern "C" void kernel_launch(void* const* d_in, const int* in_sizes, int n_in,
                              void* d_out, int out_size, void* d_ws, size_t ws_size,
                              hipStream_t stream) {
    const float* x     = (const float*)d_in[0];
    const float* w_qkv = (const float*)d_in[1];
    const float* w_out = (const float*)d_in[2];
    const float* b_out = (const float*)d_in[3];
    float* out = (float*)d_out;
    float* ws  = (float*)d_ws;

    void* args[] = {(void*)&x, (void*)&w_qkv, (void*)&w_out, (void*)&b_out,
                    (void*)&out, (void*)&ws};
    hipLaunchCooperativeKernel((const void*)mega, dim3(256), dim3(256), args, 0, stream);
}

// Round 9
// 223.665 us; speedup vs baseline: 2.3484x; 2.3484x over previous
//
#include <hip/hip_runtime.h>
#include <math.h>

#define Bsz 4
#define Nseq 2048
#define Cdim 512
#define Hn 8
#define Dh 64
#define TK 256
#define BH (Bsz*Hn)          // 32
#define MROWS (Bsz*Nseq)     // 8192
#define QKVC 1536

typedef __attribute__((ext_vector_type(8))) short bf16x8;
typedef __attribute__((ext_vector_type(4))) float f32x4;

__device__ __forceinline__ unsigned short f2bf(float x) {
    unsigned u = __float_as_uint(x);
    unsigned r = (u + 0x7fffu + ((u >> 16) & 1u)) >> 16;   // RNE
    return (unsigned short)r;
}
__device__ __forceinline__ float bf2f(unsigned short h) {
    return __uint_as_float((unsigned)h << 16);
}
__device__ __forceinline__ void split8(const float* p, bf16x8& h8, bf16x8& l8) {
    float4 u0 = *(const float4*)p;
    float4 u1 = *(const float4*)(p + 4);
    float vv[8] = {u0.x, u0.y, u0.z, u0.w, u1.x, u1.y, u1.z, u1.w};
    #pragma unroll
    for (int j = 0; j < 8; ++j) {
        unsigned short hv = f2bf(vv[j]);
        h8[j] = (short)hv;
        l8[j] = (short)f2bf(vv[j] - bf2f(hv));
    }
}

// ---------------------------------------------------------------
// prep: blocks 0..63  = x column-sum partials (per batch, 16 chunks)
//       blocks 64..447 = w_qkv -> B-fragment-packed hi/lo bf16
// ---------------------------------------------------------------
__global__ __launch_bounds__(256) void prep_kernel(const float* __restrict__ x,
                                                   const float* __restrict__ w_qkv,
                                                   bf16x8* __restrict__ Bp_hi,
                                                   bf16x8* __restrict__ Bp_lo,
                                                   float* __restrict__ xpart) {
    int bid = blockIdx.x, tid = threadIdx.x;
    if (bid < 64) {
        int b = bid >> 4, chunk = bid & 15;
        float s0 = 0.f, s1 = 0.f;
        const float* xb = x + ((size_t)b * Nseq + chunk * 128) * Cdim;
        for (int r = 0; r < 128; ++r) {
            s0 += xb[(size_t)r * Cdim + tid];
            s1 += xb[(size_t)r * Cdim + tid + 256];
        }
        xpart[(size_t)(b * 16 + chunk) * Cdim + tid] = s0;
        xpart[(size_t)(b * 16 + chunk) * Cdim + tid + 256] = s1;
    } else {
        int pid = bid - 64;
        int nt = pid % 96, ktg = pid / 96;
        int kt = ktg * 4 + (tid >> 6);
        int lane = tid & 63;
        int c = nt * 16 + (lane & 15);
        int kbase = kt * 32 + (lane >> 4) * 8;
        bf16x8 h, l;
        #pragma unroll
        for (int j = 0; j < 8; ++j) {
            float v = w_qkv[(size_t)(kbase + j) * QKVC + c];
            unsigned short hv = f2bf(v);
            h[j] = (short)hv;
            l[j] = (short)f2bf(v - bf2f(hv));
        }
        int idx = (nt * 16 + kt) * 64 + lane;
        Bp_hi[idx] = h;
        Bp_lo[idx] = l;
    }
}

// ---------------------------------------------------------------
// proj2: parallel projections. grid (68, Bsz), 256 thr.
// ---------------------------------------------------------------
__global__ __launch_bounds__(256) void proj2_kernel(const float* __restrict__ xpart,
                                                    const float* __restrict__ w_qkv,
                                                    const float* __restrict__ w_out,
                                                    const float* __restrict__ b_out,
                                                    float* __restrict__ proj,
                                                    float* __restrict__ sv_g,
                                                    float* __restrict__ ubase) {
    int j = blockIdx.x, b = blockIdx.y;
    int tid = threadIdx.x;
    __shared__ float xs[512];
    __shared__ float red[4][64];
    __shared__ float mean[64];
    __shared__ float p2[2][128];
    __shared__ float svs[512];
    {
        float s0 = 0.f, s1 = 0.f;
        for (int c16 = 0; c16 < 16; ++c16) {
            const float* xp = xpart + (size_t)(b * 16 + c16) * Cdim;
            s0 += xp[tid];
            s1 += xp[tid + 256];
        }
        xs[tid] = s0; xs[tid + 256] = s1;
    }
    __syncthreads();
    if (j < 64) {
        int slot = j >> 2, q = j & 3;
        int type = slot >> 3, h = slot & 7;
        int moff = (type ? 0 : 512) + h * 64;
        int woff = (type ? 512 : 0) + h * 64;
        {
            int d = tid & 63, kq = tid >> 6;
            float s = 0.f;
            for (int k = kq * 128; k < kq * 128 + 128; ++k)
                s += xs[k] * w_qkv[(size_t)k * QKVC + moff + d];
            red[kq][d] = s;
        }
        __syncthreads();
        if (tid < 64) mean[tid] = (red[0][tid] + red[1][tid] + red[2][tid] + red[3][tid]) * (1.0f / Nseq);
        __syncthreads();
        int c = q * 128 + (tid & 127), half = tid >> 7;
        float s = 0.f;
        const float4* wp = (const float4*)(w_qkv + (size_t)c * QKVC + woff + half * 32);
        const float4* mp = (const float4*)(mean + half * 32);
        #pragma unroll
        for (int d4 = 0; d4 < 8; ++d4) {
            float4 w4 = wp[d4], m4 = mp[d4];
            s += w4.x * m4.x + w4.y * m4.y + w4.z * m4.z + w4.w * m4.w;
        }
        p2[half][tid & 127] = s;
        __syncthreads();
        if (tid < 128)
            proj[(size_t)(b * 16 + slot) * 512 + q * 128 + tid] = p2[0][tid] + p2[1][tid];
    } else {
        int q = j - 64;
        {
            float s0 = 0.f, s1 = 0.f;
            for (int k = 0; k < 512; ++k) {
                float xv = xs[k];
                const float* wr = w_qkv + (size_t)k * QKVC + 1024;
                s0 += xv * wr[tid];
                s1 += xv * wr[tid + 256];
            }
            svs[tid] = s0; svs[tid + 256] = s1;
            if (q == 0) { sv_g[b * 512 + tid] = s0; sv_g[b * 512 + tid + 256] = s1; }
        }
        __syncthreads();
        int c = q * 128 + (tid & 127), half = tid >> 7;
        float s = 0.f;
        for (int k = half * 256; k < half * 256 + 256; ++k)
            s += svs[k] * (1.0f / Nseq) * w_out[(size_t)k * 512 + c];
        p2[half][tid & 127] = s;
        __syncthreads();
        if (tid < 128)
            ubase[b * 512 + q * 128 + tid] = p2[0][tid] + p2[1][tid] + b_out[q * 128 + tid];
    }
}

// ---------------------------------------------------------------
// score: rsc/csc = 0.125 * x @ proj.  grid (4, 32).
// ---------------------------------------------------------------
__global__ __launch_bounds__(256) void score_kernel(const float* __restrict__ x,
                                                    const float* __restrict__ proj,
                                                    float* __restrict__ rsc,
                                                    float* __restrict__ csc) {
    int b = blockIdx.x, ch = blockIdx.y;
    int tid = threadIdx.x;
    __shared__ float4 pj4[16 * 128];
    __shared__ float part[4][64][17];
    for (int i = tid; i < 2048; i += 256)
        pj4[i] = ((const float4*)(proj + (size_t)b * 16 * 512))[i];
    __syncthreads();
    int w = tid >> 6, lane = tid & 63;
    int row = ch * 64 + lane;
    const float4* xr = (const float4*)(x + ((size_t)b * Nseq + row) * Cdim + w * 128);
    float acc[16];
    #pragma unroll
    for (int s = 0; s < 16; ++s) acc[s] = 0.f;
    for (int c4 = 0; c4 < 32; ++c4) {
        float4 xv = xr[c4];
        #pragma unroll
        for (int s = 0; s < 16; ++s) {
            float4 p = pj4[s * 128 + w * 32 + c4];
            acc[s] += xv.x * p.x + xv.y * p.y + xv.z * p.z + xv.w * p.w;
        }
    }
    #pragma unroll
    for (int s = 0; s < 16; ++s) part[w][lane][s] = acc[s];
    __syncthreads();
    for (int job = tid; job < 1024; job += 256) {
        int rl = job >> 4, s = job & 15;
        float v = (part[0][rl][s] + part[1][rl][s] + part[2][rl][s] + part[3][rl][s]) * 0.125f;
        int i = ch * 64 + rl;
        int h = s & 7;
        if (s < 8) rsc[(size_t)(b * 8 + h) * Nseq + i] = v;
        else       csc[(size_t)(b * 8 + h) * Nseq + i] = v;
    }
}

// ---------------------------------------------------------------
// top-256 by rank counting; emits rankmap for ROW selection.
// ---------------------------------------------------------------
__global__ __launch_bounds__(256) void topk_kernel(const float* __restrict__ rsc,
                                                   const float* __restrict__ csc,
                                                   int* ridx, int* cidx, int* rankmap) {
    int selid = blockIdx.y;
    int bh = selid >> 1, which = selid & 1;
    const float* sin = which ? (csc + (size_t)bh * Nseq) : (rsc + (size_t)bh * Nseq);
    int* outp = which ? (cidx + bh * TK) : (ridx + bh * TK);
    __shared__ unsigned long long keys[Nseq];
    int tid = threadIdx.x;
    for (int i = tid; i < Nseq; i += 256) {
        unsigned u = __float_as_uint(sin[i]);
        u = (u & 0x80000000u) ? ~u : (u | 0x80000000u);
        keys[i] = ((unsigned long long)u << 32) | (unsigned)(Nseq - 1 - i);
    }
    __syncthreads();
    int i = blockIdx.x * 256 + tid;
    unsigned long long ki = keys[i];
    int rank = 0;
    #pragma unroll 8
    for (int j = 0; j < Nseq; ++j) rank += (keys[j] > ki) ? 1 : 0;
    if (rank < TK) outp[rank] = i;
    if (which == 0) rankmap[(size_t)bh * Nseq + i] = (rank < TK) ? rank : -1;
}

// ---------------------------------------------------------------
// gather GEMM: selected Q (which=0) or K+V (which=1), 64 rows per
// block. grid (2 which, 4 rquarter, 32 bh) = 256 blocks.
// svsel as 4 deterministic partials.
// ---------------------------------------------------------------
__global__ __launch_bounds__(256) void gather_kernel(const float* __restrict__ x,
                                                     const bf16x8* __restrict__ Bp_hi,
                                                     const bf16x8* __restrict__ Bp_lo,
                                                     const int* __restrict__ ridx,
                                                     const int* __restrict__ cidx,
                                                     float* __restrict__ Qs_g,
                                                     float* __restrict__ Kt_g,
                                                     float* __restrict__ Vs_g,
                                                     float* __restrict__ svsel_g) {
    int which = blockIdx.x, rh = blockIdx.y, bh = blockIdx.z;
    int b = bh >> 3, h = bh & 7;
    int tid = threadIdx.x, wv = tid >> 6, lane = tid & 63;
    __shared__ float red[4][64];
    const int* idx = (which == 0 ? ridx : cidx) + bh * TK;
    int sel = idx[rh * 64 + wv * 16 + (lane & 15)];
    const float* ap = x + ((size_t)(b * Nseq + sel)) * Cdim + ((lane >> 4) * 8);
    int cl = lane & 15, rq = (lane >> 4) * 4;

    if (which == 0) {
        f32x4 acc[4];
        #pragma unroll
        for (int c = 0; c < 4; ++c) acc[c] = (f32x4){0.f, 0.f, 0.f, 0.f};
        #pragma unroll 2
        for (int kt = 0; kt < 16; ++kt) {
            bf16x8 ah, al, bh8[4], bl8[4];
            split8(ap + kt * 32, ah, al);
            #pragma unroll
            for (int ni = 0; ni < 4; ++ni) {
                int bi = ((h * 4 + ni) * 16 + kt) * 64 + lane;
                bh8[ni] = Bp_hi[bi]; bl8[ni] = Bp_lo[bi];
            }
            #pragma unroll
            for (int ni = 0; ni < 4; ++ni) {
                acc[ni] = __builtin_amdgcn_mfma_f32_16x16x32_bf16(ah, bh8[ni], acc[ni], 0, 0, 0);
                acc[ni] = __builtin_amdgcn_mfma_f32_16x16x32_bf16(ah, bl8[ni], acc[ni], 0, 0, 0);
                acc[ni] = __builtin_amdgcn_mfma_f32_16x16x32_bf16(al, bh8[ni], acc[ni], 0, 0, 0);
            }
        }
        #pragma unroll
        for (int ni = 0; ni < 4; ++ni)
            #pragma unroll
            for (int r = 0; r < 4; ++r) {
                int row = rh * 64 + wv * 16 + rq + r;
                Qs_g[((size_t)bh * TK + row) * 64 + ni * 16 + cl] = acc[ni][r];
            }
    } else {
        f32x4 acc[8];
        #pragma unroll
        for (int c = 0; c < 8; ++c) acc[c] = (f32x4){0.f, 0.f, 0.f, 0.f};
        #pragma unroll 2
        for (int kt = 0; kt < 16; ++kt) {
            bf16x8 ah, al, bh8[8], bl8[8];
            split8(ap + kt * 32, ah, al);
            #pragma unroll
            for (int ni = 0; ni < 8; ++ni) {
                int nt16 = (ni < 4) ? (32 + h * 4 + ni) : (64 + h * 4 + (ni - 4));
                int bi = (nt16 * 16 + kt) * 64 + lane;
                bh8[ni] = Bp_hi[bi]; bl8[ni] = Bp_lo[bi];
            }
            #pragma unroll
            for (int ni = 0; ni < 8; ++ni) {
                acc[ni] = __builtin_amdgcn_mfma_f32_16x16x32_bf16(ah, bh8[ni], acc[ni], 0, 0, 0);
                acc[ni] = __builtin_amdgcn_mfma_f32_16x16x32_bf16(ah, bl8[ni], acc[ni], 0, 0, 0);
                acc[ni] = __builtin_amdgcn_mfma_f32_16x16x32_bf16(al, bh8[ni], acc[ni], 0, 0, 0);
            }
        }
        #pragma unroll
        for (int ni = 0; ni < 4; ++ni) {
            int d = ni * 16 + cl;
            #pragma unroll
            for (int r = 0; r < 4; ++r) {
                int row = rh * 64 + wv * 16 + rq + r;
                Kt_g[((size_t)bh * 64 + d) * TK + row] = acc[ni][r];
            }
        }
        #pragma unroll
        for (int ni = 0; ni < 4; ++ni) {
            int d = ni * 16 + cl;
            float s = 0.f;
            #pragma unroll
            for (int r = 0; r < 4; ++r) {
                int row = rh * 64 + wv * 16 + rq + r;
                Vs_g[((size_t)bh * TK + row) * 64 + d] = acc[4 + ni][r];
                s += acc[4 + ni][r];
            }
            s += __shfl_xor(s, 16, 64);
            s += __shfl_xor(s, 32, 64);
            if (lane < 16) red[wv][ni * 16 + lane] = s;
        }
        __syncthreads();
        if (tid < 64)
            svsel_g[(bh * 4 + rh) * 64 + tid] = red[0][tid] + red[1][tid] + red[2][tid] + red[3][tid];
    }
}

// ---------------------------------------------------------------
// attn + deltamm fused: grid (32 bh, 16 rblk) = 512 blocks, 16 Q-rows
// per block. K^T / V streamed from global (L2-hot, coalesced).
// LDS: E[16][256] + Q[16][64] + delta[16][64] = 24 KB -> 2 blocks/CU.
// Writes deltaout[bh][256][512] directly (delta never hits HBM).
// ---------------------------------------------------------------
__global__ __launch_bounds__(256) void attn_dmm(const float* __restrict__ Qs_g,
                                                const float* __restrict__ Kt_g,
                                                const float* __restrict__ Vs_g,
                                                const float* __restrict__ sv_g,
                                                const float* __restrict__ svsel_g,
                                                const float* __restrict__ w_out,
                                                float* __restrict__ deltaout) {
    int bh = blockIdx.x, rblk = blockIdx.y;
    int b = bh >> 3, h = bh & 7;
    int tid = threadIdx.x, wave = tid >> 6, lane = tid & 63;
    __shared__ float E[16 * 256];      // 16 KB
    __shared__ float4 Qs4[16 * 16];    // 4 KB
    __shared__ float dQ[16 * 64];      // 4 KB
    {
        const float4* qs = (const float4*)(Qs_g + ((size_t)bh * TK + rblk * 16) * 64);
        if (tid < 256) Qs4[tid] = qs[tid];
    }
    __syncthreads();

    int iw0 = wave * 4;
    const float4* kt4 = (const float4*)(Kt_g + (size_t)bh * 64 * TK);
    const float4* E4r;
    // ---- E phase: lane owns cols 4*lane..+3 for its wave's 4 rows
    float e[4][4];
    #pragma unroll
    for (int r = 0; r < 4; ++r)
        #pragma unroll
        for (int c = 0; c < 4; ++c) e[r][c] = 0.f;
    for (int d4 = 0; d4 < 16; ++d4) {
        float4 k0 = kt4[(4 * d4 + 0) * 64 + lane];
        float4 k1 = kt4[(4 * d4 + 1) * 64 + lane];
        float4 k2 = kt4[(4 * d4 + 2) * 64 + lane];
        float4 k3 = kt4[(4 * d4 + 3) * 64 + lane];
        #pragma unroll
        for (int r = 0; r < 4; ++r) {
            float4 q4 = Qs4[(iw0 + r) * 16 + d4];
            e[r][0] += q4.x * k0.x + q4.y * k1.x + q4.z * k2.x + q4.w * k3.x;
            e[r][1] += q4.x * k0.y + q4.y * k1.y + q4.z * k2.y + q4.w * k3.y;
            e[r][2] += q4.x * k0.z + q4.y * k1.z + q4.z * k2.z + q4.w * k3.z;
            e[r][3] += q4.x * k0.w + q4.y * k1.w + q4.z * k2.w + q4.w * k3.w;
        }
    }
    float um[4], iz[4];
    #pragma unroll
    for (int r = 0; r < 4; ++r) {
        float s0 = e[r][0] * 0.125f, s1 = e[r][1] * 0.125f;
        float s2 = e[r][2] * 0.125f, s3 = e[r][3] * 0.125f;
        float mx = fmaxf(fmaxf(s0, s1), fmaxf(s2, s3));
        #pragma unroll
        for (int off = 32; off; off >>= 1) mx = fmaxf(mx, __shfl_xor(mx, off, 64));
        mx = fmaxf(mx, 0.0f);
        float e0 = __expf(s0 - mx), e1 = __expf(s1 - mx);
        float e2 = __expf(s2 - mx), e3 = __expf(s3 - mx);
        float zs = e0 + e1 + e2 + e3;
        #pragma unroll
        for (int off = 32; off; off >>= 1) zs += __shfl_xor(zs, off, 64);
        um[r] = __expf(-mx);
        iz[r] = 1.0f / ((float)(Nseq - TK) * um[r] + zs);
        *(float4*)&E[(iw0 + r) * 256 + 4 * lane] = (float4){e0, e1, e2, e3};
    }
    __syncthreads();

    // ---- PV phase: lane owns output dim d = lane
    float svd = sv_g[b * 512 + h * 64 + lane];
    float sadj = svd - (svsel_g[(bh * 4 + 0) * 64 + lane] + svsel_g[(bh * 4 + 1) * 64 + lane] +
                        svsel_g[(bh * 4 + 2) * 64 + lane] + svsel_g[(bh * 4 + 3) * 64 + lane]);
    float uval = svd * (1.0f / Nseq);
    const float* vsg = Vs_g + (size_t)bh * TK * 64;
    E4r = (const float4*)E;
    float acc[4];
    #pragma unroll
    for (int r = 0; r < 4; ++r) acc[r] = 0.f;
    for (int j4 = 0; j4 < 64; ++j4) {
        float v0 = vsg[(4 * j4 + 0) * 64 + lane];
        float v1 = vsg[(4 * j4 + 1) * 64 + lane];
        float v2 = vsg[(4 * j4 + 2) * 64 + lane];
        float v3 = vsg[(4 * j4 + 3) * 64 + lane];
        #pragma unroll
        for (int r = 0; r < 4; ++r) {
            float4 e4 = E4r[(iw0 + r) * 64 + j4];
            acc[r] += e4.x * v0 + e4.y * v1 + e4.z * v2 + e4.w * v3;
        }
    }
    #pragma unroll
    for (int r = 0; r < 4; ++r) {
        float outv = (um[r] * sadj + acc[r]) * iz[r];
        dQ[(iw0 + r) * 64 + lane] = outv - uval;
    }
    __syncthreads();

    // ---- deltamm: rows iw0..iw0+3 of delta(16x64) @ w_out_h(64x512)
    float dacc[4][8];
    #pragma unroll
    for (int r = 0; r < 4; ++r)
        #pragma unroll
        for (int c = 0; c < 8; ++c) dacc[r][c] = 0.f;
    const float* wbase = w_out + (size_t)(h * 64) * 512 + lane * 8;
    for (int k = 0; k < 64; ++k) {
        float4 wa = *(const float4*)(wbase + (size_t)k * 512);
        float4 wb = *(const float4*)(wbase + (size_t)k * 512 + 4);
        #pragma unroll
        for (int r = 0; r < 4; ++r) {
            float dv = dQ[(iw0 + r) * 64 + k];
            dacc[r][0] += dv * wa.x; dacc[r][1] += dv * wa.y;
            dacc[r][2] += dv * wa.z; dacc[r][3] += dv * wa.w;
            dacc[r][4] += dv * wb.x; dacc[r][5] += dv * wb.y;
            dacc[r][6] += dv * wb.z; dacc[r][7] += dv * wb.w;
        }
    }
    #pragma unroll
    for (int r = 0; r < 4; ++r) {
        int row = rblk * 16 + iw0 + r;
        float* dp = deltaout + ((size_t)bh * TK + row) * 512 + lane * 8;
        *(float4*)dp = (float4){dacc[r][0], dacc[r][1], dacc[r][2], dacc[r][3]};
        *(float4*)(dp + 4) = (float4){dacc[r][4], dacc[r][5], dacc[r][6], dacc[r][7]};
    }
}

// ---------------------------------------------------------------
// out[b][i][:] = ubase[b][:] + sum_h deltaout[bh][rankmap[bh][i]][:]
// ---------------------------------------------------------------
__global__ __launch_bounds__(256) void compose(const float* __restrict__ ubase,
                                               const int* __restrict__ rankmap,
                                               const float* __restrict__ deltaout,
                                               float* __restrict__ out) {
    int r0 = blockIdx.x * 4;
    int b = r0 >> 11;
    int tid = threadIdx.x;
    float u0 = ubase[b * 512 + tid];
    float u1 = ubase[b * 512 + 256 + tid];
    for (int rr = 0; rr < 4; ++rr) {
        int i = (r0 + rr) & 2047;
        float a0 = u0, a1 = u1;
        #pragma unroll
        for (int h = 0; h < 8; ++h) {
            int rk = rankmap[(size_t)(b * 8 + h) * Nseq + i];
            if (rk >= 0) {
                const float* dp = deltaout + ((size_t)(b * 8 + h) * TK + rk) * 512;
                a0 += dp[tid];
                a1 += dp[256 + tid];
            }
        }
        float* op = out + ((size_t)b * Nseq + i) * 512;
        op[tid] = a0;
        op[256 + tid] = a1;
    }
}

extern "C" void kernel_launch(void* const* d_in, const int* in_sizes, int n_in,
                              void* d_out, int out_size, void* d_ws, size_t ws_size,
                              hipStream_t stream) {
    const float* x     = (const float*)d_in[0];
    const float* w_qkv = (const float*)d_in[1];
    const float* w_out = (const float*)d_in[2];
    const float* b_out = (const float*)d_in[3];
    float* out = (float*)d_out;

    float* ws = (float*)d_ws;
    bf16x8* Bp_hi = (bf16x8*)ws;                                  // 393,216 f
    bf16x8* Bp_lo = (bf16x8*)(ws + 393216);                       // 393,216 f
    float* xpart  = ws + 786432;                                  // 32,768 f
    float* proj   = xpart + 32768;                                // 32,768 f
    float* sv_g   = proj + 32768;                                 // 2,048 f
    float* svsel  = sv_g + 2048;                                  // 8,192 f (4 partials)
    float* ubase  = svsel + 8192;                                 // 2,048 f
    float* rsc    = ubase + 2048;                                 // 65,536 f
    float* csc    = rsc + (size_t)BH * Nseq;                      // 65,536 f
    int*   ridx   = (int*)(csc + (size_t)BH * Nseq);              // 8,192 i
    int*   cidx   = ridx + BH * TK;                               // 8,192 i
    int*   rankmap = cidx + BH * TK;                              // 65,536 i
    float* Qs_g   = (float*)(rankmap + (size_t)BH * Nseq);        // 524,288 f
    float* Kt_g   = Qs_g + (size_t)BH * TK * 64;                  // 524,288 f
    float* Vs_g   = Kt_g + (size_t)BH * TK * 64;                  // 524,288 f
    float* deltaout = Vs_g + (size_t)BH * TK * 64;                // 4,194,304 f

    // 1. x column-sum partials + w_qkv fragment packing
    prep_kernel<<<448, 256, 0, stream>>>(x, w_qkv, Bp_hi, Bp_lo, xpart);
    // 2. projections, sv, ubase
    proj2_kernel<<<dim3(68, Bsz), 256, 0, stream>>>(xpart, w_qkv, w_out, b_out, proj, sv_g, ubase);
    // 3. rank-1 scores straight from x
    score_kernel<<<dim3(Bsz, 32), 256, 0, stream>>>(x, proj, rsc, csc);
    // 4. top-256 + rankmap
    topk_kernel<<<dim3(Nseq / 256, BH * 2), 256, 0, stream>>>(rsc, csc, ridx, cidx, rankmap);
    // 5. selected Q / K^T / V via gathered split-bf16 MFMA (+svsel partials)
    gather_kernel<<<dim3(2, 4, BH), 256, 0, stream>>>(x, Bp_hi, Bp_lo, ridx, cidx,
                                                      Qs_g, Kt_g, Vs_g, svsel);
    // 6. fused attention + delta @ w_out (delta stays in LDS)
    attn_dmm<<<dim3(BH, 16), 256, 0, stream>>>(Qs_g, Kt_g, Vs_g, sv_g, svsel, w_out, deltaout);
    // 7. compose final output
    compose<<<MROWS / 4, 256, 0, stream>>>(ubase, rankmap, deltaout, out);
}